// Round 5
// baseline (8210.744 us; speedup 1.0000x reference)
//
#include <hip/hip_runtime.h>

#define NB 8
#define NN 4096
#define MM 4096
#define CC 256

typedef unsigned short u16;
typedef __attribute__((ext_vector_type(4))) unsigned short u16x4;
typedef __attribute__((ext_vector_type(8))) short s16x8;
typedef __attribute__((ext_vector_type(4))) float f32x4;

#define INV_EPS 33.333333333333336f
#define POWER   0.94339622641509435f   /* 0.5/(0.5+0.03) */
#define PROB    (1.0f/4096.0f)

static __device__ __forceinline__ float bf2f(u16 h) {
    union { unsigned int u; float f; } v;
    v.u = ((unsigned int)h) << 16;
    return v.f;
}
static __device__ __forceinline__ u16 f2bf(float f) {
    union { float f; unsigned int u; } v;
    v.f = f;
    unsigned int u = v.u;
    u += 0x7fffu + ((u >> 16) & 1u);   // round-to-nearest-even
    return (u16)(u >> 16);
}

// ---------------------------------------------------------------------------
// L2-normalize rows of (rows x 256) fp32 -> bf16. One wave per row.
// ---------------------------------------------------------------------------
__global__ __launch_bounds__(256) void norm_kernel(const float* __restrict__ src,
                                                   u16* __restrict__ dst)
{
    const int t = threadIdx.x, w = t >> 6, lane = t & 63;
    const size_t row = (size_t)blockIdx.x * 4 + w;
    const float* sp = src + row * CC + lane * 4;
    f32x4 v = *(const f32x4*)sp;
    float s = v.x * v.x + v.y * v.y + v.z * v.z + v.w * v.w;
    for (int o = 32; o > 0; o >>= 1) s += __shfl_xor(s, o);
    float rn = rsqrtf(s + 1e-8f);
    u16x4 o4;
    o4.x = f2bf(v.x * rn); o4.y = f2bf(v.y * rn);
    o4.z = f2bf(v.z * rn); o4.w = f2bf(v.w * rn);
    *(u16x4*)(dst + row * CC + lane * 4) = o4;
}

// ---------------------------------------------------------------------------
// zero KTa (d_ws is poisoned 0xAA before every call)
// ---------------------------------------------------------------------------
__global__ __launch_bounds__(256) void zero_kernel(float* __restrict__ KTa)
{
    KTa[blockIdx.x * 256 + threadIdx.x] = 0.f;
}

// ---------------------------------------------------------------------------
// Strip GEMM: Ks[ls][r][c] = exp((f1s[ls][r]·f2s[ls][c] - 1)/eps), bf16 out.
// Epilogue accumulates iteration-1 KTa = PROB * colsum(K) (a0 uniform).
// ---------------------------------------------------------------------------
#define LDSS 72   /* 64 + 8 pad, in u16 units */

__global__ __launch_bounds__(256, 2) void gemm_exp_kernel(
    const u16* __restrict__ f1s, const u16* __restrict__ f2s,
    u16* __restrict__ Ks, float* __restrict__ KTa)
{
    const int t = threadIdx.x;
    const int w = t >> 6, lane = t & 63;
    const int quad = lane >> 4, l15 = lane & 15;
    const int bx = blockIdx.x;   // c-tile (f2 rows)
    const int by = blockIdx.y;   // r-tile (f1 rows)
    const int ls = blockIdx.z;   // local batch in strip

    __shared__ u16 As[128 * LDSS];
    __shared__ u16 Bs[128 * LDSS];
    __shared__ float csum[128];

    if (t < 128) csum[t] = 0.f;   // covered by first loop's __syncthreads

    const u16* f2base = f2s + ((size_t)ls * MM + (size_t)bx * 128) * CC;
    const u16* f1base = f1s + ((size_t)ls * NN + (size_t)by * 128) * CC;

    f32x4 acc[4][4];
#pragma unroll
    for (int i = 0; i < 4; ++i)
#pragma unroll
        for (int j = 0; j < 4; ++j) acc[i][j] = (f32x4){0.f, 0.f, 0.f, 0.f};

    const int g_r = t >> 3;
    const int g_c = (t & 7) << 3;

    for (int kt = 0; kt < 4; ++kt) {
        const int k0 = kt * 64;
        __syncthreads();
#pragma unroll
        for (int i = 0; i < 4; ++i) {
            const int row = g_r + i * 32;
            s16x8 va = *(const s16x8*)(f2base + (size_t)row * CC + k0 + g_c);
            s16x8 vb = *(const s16x8*)(f1base + (size_t)row * CC + k0 + g_c);
            *(s16x8*)&As[row * LDSS + g_c] = va;
            *(s16x8*)&Bs[row * LDSS + g_c] = vb;
        }
        __syncthreads();
#pragma unroll
        for (int s = 0; s < 2; ++s) {
            s16x8 af[4], bfr[4];
#pragma unroll
            for (int i = 0; i < 4; ++i)
                af[i] = *(const s16x8*)&As[((w & 1) * 64 + i * 16 + l15) * LDSS + s * 32 + quad * 8];
#pragma unroll
            for (int j = 0; j < 4; ++j)
                bfr[j] = *(const s16x8*)&Bs[((w >> 1) * 64 + j * 16 + l15) * LDSS + s * 32 + quad * 8];
#pragma unroll
            for (int i = 0; i < 4; ++i)
#pragma unroll
                for (int j = 0; j < 4; ++j)
                    acc[i][j] = __builtin_amdgcn_mfma_f32_16x16x32_bf16(af[i], bfr[j], acc[i][j], 0, 0, 0);
        }
    }

    u16* kb = Ks + (size_t)ls * NN * MM;
    const int rbase = by * 128 + (w >> 1) * 64 + l15;
    const int cbase = bx * 128 + (w & 1) * 64 + quad * 4;
    float part[4][4];
#pragma unroll
    for (int i = 0; i < 4; ++i)
#pragma unroll
        for (int e = 0; e < 4; ++e) part[i][e] = 0.f;

#pragma unroll
    for (int j = 0; j < 4; ++j) {
        const int r = rbase + j * 16;
#pragma unroll
        for (int i = 0; i < 4; ++i) {
            const int c = cbase + i * 16;
            f32x4 v = acc[i][j];
            const float e0 = expf((v.x - 1.f) * INV_EPS);
            const float e1 = expf((v.y - 1.f) * INV_EPS);
            const float e2 = expf((v.z - 1.f) * INV_EPS);
            const float e3 = expf((v.w - 1.f) * INV_EPS);
            u16x4 o;
            o.x = f2bf(e0); o.y = f2bf(e1); o.z = f2bf(e2); o.w = f2bf(e3);
            *(u16x4*)&kb[(size_t)r * MM + c] = o;
            part[i][0] += e0; part[i][1] += e1; part[i][2] += e2; part[i][3] += e3;
        }
    }

#pragma unroll
    for (int i = 0; i < 4; ++i)
#pragma unroll
        for (int e = 0; e < 4; ++e) {
            float v = part[i][e];
            v += __shfl_xor(v, 1); v += __shfl_xor(v, 2);
            v += __shfl_xor(v, 4); v += __shfl_xor(v, 8);
            if (l15 == 0)
                atomicAdd(&csum[(w & 1) * 64 + i * 16 + quad * 4 + e], v);
        }
    __syncthreads();
    if (t < 128)
        atomicAdd(&KTa[(size_t)ls * MM + bx * 128 + t], csum[t] * PROB);
}

// b = (prob2 / (KTa + 1e-8))^power ; re-zero KTa for next fused pass
__global__ __launch_bounds__(256) void bfin_kernel(float* __restrict__ KTa,
                                                   float* __restrict__ bvec)
{
    const int t = blockIdx.x * 256 + threadIdx.x;
    const float v = KTa[t];
    KTa[t] = 0.f;
    bvec[t] = powf(PROB / (v + 1e-8f), POWER);
}

// ---------------------------------------------------------------------------
// FUSED iteration pass (v4): ONE read of K per Sinkhorn iteration.
// Per row n:  S = sum_m K[n][m]*b[m];  a_n = (PROB/(S+1e-8))^power;
//             kacc[m] += a_n * K[n][m]   <-- directly in LDS (ds_add_f32),
// NO per-thread accumulator array -> ~50 live VGPRs, nothing to spill.
// kacc XOR-swizzled so the stride-8 ownership is <=2-way bank conflict (free).
// grid = cnt*128 (32 rows/block), block = 256 (4 waves, 8 rows/wave).
// ---------------------------------------------------------------------------
__global__ __launch_bounds__(256) void fused_kernel(const u16* __restrict__ Ks,
                                                    const float* __restrict__ bvec,
                                                    float* __restrict__ KTa)
{
    const int t = threadIdx.x, w = t >> 6, lane = t & 63;
    const int ls = blockIdx.x >> 7;
    const int chunk = blockIdx.x & 127;

    __shared__ float kacc[4096];   // 16 KB: swizzled column accumulator
    __shared__ float bvs[4096];    // 16 KB: b vector (plain layout)

#pragma unroll
    for (int i = 0; i < 16; ++i) kacc[i * 256 + t] = 0.f;
    {
        const float* bp = bvec + ls * MM;
#pragma unroll
        for (int i = 0; i < 4; ++i)
            *(f32x4*)&bvs[i * 1024 + t * 4] = *(const f32x4*)(bp + i * 1024 + t * 4);
    }
    __syncthreads();

    const u16* kbase = Ks + ((size_t)ls * NN + (size_t)chunk * 32) * MM + lane * 8;

    for (int rr = 0; rr < 8; ++rr) {
        const u16* kp = kbase + (size_t)(rr * 4 + w) * MM;
        s16x8 kv[8];
#pragma unroll
        for (int k = 0; k < 8; ++k) kv[k] = *(const s16x8*)(kp + (size_t)k * 512);

        float s = 0.f;
#pragma unroll
        for (int k = 0; k < 8; ++k) {
            f32x4 b0 = *(const f32x4*)&bvs[k * 512 + lane * 8];
            f32x4 b1 = *(const f32x4*)&bvs[k * 512 + lane * 8 + 4];
            const u16* ku = (const u16*)&kv[k];
            s += bf2f(ku[0]) * b0.x + bf2f(ku[1]) * b0.y
               + bf2f(ku[2]) * b0.z + bf2f(ku[3]) * b0.w
               + bf2f(ku[4]) * b1.x + bf2f(ku[5]) * b1.y
               + bf2f(ku[6]) * b1.z + bf2f(ku[7]) * b1.w;
        }
#pragma unroll
        for (int o = 32; o > 0; o >>= 1) s += __shfl_xor(s, o);
        const float ar = exp2f(POWER * log2f(PROB / (s + 1e-8f)));

#pragma unroll
        for (int k = 0; k < 8; ++k) {
            const u16* ku = (const u16*)&kv[k];
#pragma unroll
            for (int j = 0; j < 8; ++j) {
                const int col = k * 512 + lane * 8 + j;
                const int sw = col ^ ((col >> 5) & 31);
                atomicAdd(&kacc[sw], ar * bf2f(ku[j]));
            }
        }
    }
    __syncthreads();

    // coalesced flush: instruction i covers 256 consecutive columns
    float* kout = KTa + (size_t)ls * MM;
#pragma unroll
    for (int i = 0; i < 16; ++i) {
        const int c = i * 256 + t;
        const int sw = c ^ ((c >> 5) & 31);
        atomicAdd(&kout[c], kacc[sw]);
    }
}

// bp4[ls][m] = { b, b*p2x, b*p2y, b*p2z }
__global__ __launch_bounds__(256) void bp4_kernel(const float* __restrict__ bvec,
                                                  const float* __restrict__ p2,
                                                  float* __restrict__ bp4)
{
    const int t = blockIdx.x * 256 + threadIdx.x;
    const float bv = bvec[t];
    const float x = p2[(size_t)t * 3 + 0];
    const float y = p2[(size_t)t * 3 + 1];
    const float z = p2[(size_t)t * 3 + 2];
    f32x4 o = {bv, bv * x, bv * y, bv * z};
    *(f32x4*)&bp4[(size_t)t * 4] = o;
}

// ---------------------------------------------------------------------------
// Final pass: per row n, y_k = sum_m K[n][m]*bp4[m][k]; s0 = Kb (final b),
// a_10 derived in-place. wc4 = { corr_x, corr_y, corr_z, weight }.
// ---------------------------------------------------------------------------
__global__ __launch_bounds__(256) void final_kernel(const u16* __restrict__ Ks,
                                                    const float* __restrict__ bp4,
                                                    float* __restrict__ wc4)
{
    const int t = threadIdx.x, w = t >> 6, lane = t & 63;
    const int R = blockIdx.x * 4 + w;
    const int ls = R >> 12, n = R & 4095;
    const u16* kp = Ks + ((size_t)ls * NN + n) * MM + lane * 8;
    const float* pp = bp4 + (size_t)ls * MM * 4;
    float s0 = 0.f, s1 = 0.f, s2 = 0.f, s3 = 0.f;
    for (int pass = 0; pass < 8; ++pass) {
        const int m = pass * 512 + lane * 8;
        s16x8 k8 = *(const s16x8*)(kp + pass * 512);
#pragma unroll
        for (int e = 0; e < 8; ++e) {
            const float kv = bf2f(((const u16*)&k8)[e]);
            f32x4 p = *(const f32x4*)&pp[(size_t)(m + e) * 4];
            s0 += kv * p.x; s1 += kv * p.y; s2 += kv * p.z; s3 += kv * p.w;
        }
    }
    for (int o = 32; o > 0; o >>= 1) {
        s0 += __shfl_xor(s0, o); s1 += __shfl_xor(s1, o);
        s2 += __shfl_xor(s2, o); s3 += __shfl_xor(s3, o);
    }
    if (lane == 0) {
        const float av = powf(PROB / (s0 + 1e-8f), POWER);
        const float wgt = av * s0;
        const float inv = 1.f / (wgt + 1e-8f);
        f32x4 o = {av * s1 * inv, av * s2 * inv, av * s3 * inv, wgt};
        *(f32x4*)&wc4[((size_t)ls * NN + n) * 4] = o;
    }
}

// ---------------------------------------------------------------------------
// Weighted Kabsch per batch: fp64 reduction + one-sided Jacobi SVD (3x3)
// ---------------------------------------------------------------------------
__global__ __launch_bounds__(256) void kabsch_kernel(const float* __restrict__ wc4,
                                                     const float* __restrict__ p1,
                                                     float* __restrict__ out)
{
    const int b = blockIdx.x;
    const int t = threadIdx.x, w = t >> 6, lane = t & 63;
    double acc[16];
#pragma unroll
    for (int k = 0; k < 16; ++k) acc[k] = 0.0;

    for (int n = t; n < NN; n += 256) {
        const float* wp = wc4 + ((size_t)b * NN + n) * 4;
        const float cx = wp[0], cy = wp[1], cz = wp[2], wgt = wp[3];
        const float* pp = p1 + ((size_t)b * NN + n) * 3;
        const double px = pp[0], py = pp[1], pz = pp[2];
        const double wd = wgt;
        const double wcx = wd * cx, wcy = wd * cy, wcz = wd * cz;
        acc[0] += wd;
        acc[1] += wd * px; acc[2] += wd * py; acc[3] += wd * pz;
        acc[4] += wcx;     acc[5] += wcy;     acc[6] += wcz;
        acc[7]  += px * wcx; acc[8]  += px * wcy; acc[9]  += px * wcz;
        acc[10] += py * wcx; acc[11] += py * wcy; acc[12] += py * wcz;
        acc[13] += pz * wcx; acc[14] += pz * wcy; acc[15] += pz * wcz;
    }

    __shared__ double red[4][16];
#pragma unroll
    for (int k = 0; k < 16; ++k) {
        double v = acc[k];
        for (int o = 32; o > 0; o >>= 1) v += __shfl_xor(v, o);
        acc[k] = v;
    }
    if (lane == 0)
        for (int k = 0; k < 16; ++k) red[w][k] = acc[k];
    __syncthreads();

    if (t == 0) {
        double S[16];
        for (int k = 0; k < 16; ++k)
            S[k] = red[0][k] + red[1][k] + red[2][k] + red[3][k];
        const double denom = S[0] + 1e-5;
        const double sfrac = S[0] / denom;
        double ca[3] = {S[1] / denom, S[2] / denom, S[3] / denom};
        double cb[3] = {S[4] / denom, S[5] / denom, S[6] / denom};
        double A[3][3], V[3][3];
        for (int i = 0; i < 3; ++i)
            for (int j = 0; j < 3; ++j) {
                A[i][j] = S[7 + i * 3 + j] / denom - (2.0 - sfrac) * ca[i] * cb[j];
                V[i][j] = (i == j) ? 1.0 : 0.0;
            }
        for (int sweep = 0; sweep < 20; ++sweep) {
            const int PP[3] = {0, 0, 1}, QQ[3] = {1, 2, 2};
            for (int r = 0; r < 3; ++r) {
                const int p = PP[r], q = QQ[r];
                double app = 0, aqq = 0, apq = 0;
                for (int i = 0; i < 3; ++i) {
                    app += A[i][p] * A[i][p];
                    aqq += A[i][q] * A[i][q];
                    apq += A[i][p] * A[i][q];
                }
                if (fabs(apq) < 1e-14 * (app + aqq) + 1e-300) continue;
                const double th = 0.5 * atan2(2.0 * apq, app - aqq);
                const double c = cos(th), sn = sin(th);
                for (int i = 0; i < 3; ++i) {
                    double x = A[i][p], y = A[i][q];
                    A[i][p] = c * x + sn * y; A[i][q] = -sn * x + c * y;
                    x = V[i][p]; y = V[i][q];
                    V[i][p] = c * x + sn * y; V[i][q] = -sn * x + c * y;
                }
            }
        }
        double sv[3];
        for (int j = 0; j < 3; ++j)
            sv[j] = sqrt(A[0][j] * A[0][j] + A[1][j] * A[1][j] + A[2][j] * A[2][j]);
        int idx[3] = {0, 1, 2};
        if (sv[idx[0]] < sv[idx[1]]) { int x = idx[0]; idx[0] = idx[1]; idx[1] = x; }
        if (sv[idx[0]] < sv[idx[2]]) { int x = idx[0]; idx[0] = idx[2]; idx[2] = x; }
        if (sv[idx[1]] < sv[idx[2]]) { int x = idx[1]; idx[1] = idx[2]; idx[2] = x; }
        double U[3][3], Vs[3][3];
        for (int j = 0; j < 3; ++j) {
            const int jj = idx[j];
            const double inv = 1.0 / fmax(sv[jj], 1e-300);
            for (int i = 0; i < 3; ++i) {
                U[i][j] = A[i][jj] * inv;
                Vs[i][j] = V[i][jj];
            }
        }
        double R[3][3];
        for (int i = 0; i < 3; ++i)
            for (int j = 0; j < 3; ++j)
                R[i][j] = Vs[i][0] * U[j][0] + Vs[i][1] * U[j][1] + Vs[i][2] * U[j][2];
        const double det = R[0][0] * (R[1][1] * R[2][2] - R[1][2] * R[2][1])
                         - R[0][1] * (R[1][0] * R[2][2] - R[1][2] * R[2][0])
                         + R[0][2] * (R[1][0] * R[2][1] - R[1][1] * R[2][0]);
        if (det < 0.0) {
            for (int i = 0; i < 3; ++i) Vs[i][2] = -Vs[i][2];
            for (int i = 0; i < 3; ++i)
                for (int j = 0; j < 3; ++j)
                    R[i][j] = Vs[i][0] * U[j][0] + Vs[i][1] * U[j][1] + Vs[i][2] * U[j][2];
        }
        double tr[3];
        for (int i = 0; i < 3; ++i)
            tr[i] = cb[i] - (R[i][0] * ca[0] + R[i][1] * ca[1] + R[i][2] * ca[2]);
        float* o = out + b * 12;
        for (int i = 0; i < 3; ++i) {
            o[i * 4 + 0] = (float)R[i][0];
            o[i * 4 + 1] = (float)R[i][1];
            o[i * 4 + 2] = (float)R[i][2];
            o[i * 4 + 3] = (float)tr[i];
        }
    }
}

// ---------------------------------------------------------------------------
extern "C" void kernel_launch(void* const* d_in, const int* in_sizes, int n_in,
                              void* d_out, int out_size, void* d_ws, size_t ws_size,
                              hipStream_t stream) {
    const float* f1 = (const float*)d_in[0];
    const float* f2 = (const float*)d_in[1];
    const float* p1 = (const float*)d_in[2];
    const float* p2 = (const float*)d_in[3];
    float* out = (float*)d_out;

    const size_t AL = 256;
    const size_t szK   = (size_t)NN * MM * 2;
    const size_t szF1  = (size_t)NN * CC * 2;
    const size_t szF2  = (size_t)MM * CC * 2;
    const size_t szB   = (size_t)MM * 4;
    const size_t szKTa = (size_t)MM * 4;
    const size_t szBp4 = (size_t)MM * 16;
    const size_t szWc4 = (size_t)NN * 16;
    const size_t per_batch = szK + szF1 + szF2 + szB + szKTa + szBp4 + szWc4 + 8 * AL;

    int NS = (int)(ws_size / per_batch);
    if (NS > NB) NS = NB;
    if (NS < 1) NS = 1;

    char* base = (char*)d_ws;
    size_t off = 0;
    auto carve = [&](size_t bytes) -> char* {
        char* p = base + off;
        off += (bytes + AL - 1) & ~(AL - 1);
        return p;
    };
    u16*   Ks   = (u16*)  carve((size_t)NS * szK);
    u16*   f1s  = (u16*)  carve((size_t)NS * szF1);
    u16*   f2s  = (u16*)  carve((size_t)NS * szF2);
    float* bvec = (float*)carve((size_t)NS * szB);
    float* KTa  = (float*)carve((size_t)NS * szKTa);
    float* bp4  = (float*)carve((size_t)NS * szBp4);
    float* wc4  = (float*)carve((size_t)NS * szWc4);

    for (int b0 = 0; b0 < NB; b0 += NS) {
        const int cnt = (NB - b0 < NS) ? (NB - b0) : NS;

        norm_kernel<<<cnt * NN / 4, 256, 0, stream>>>(f1 + (size_t)b0 * NN * CC, f1s);
        norm_kernel<<<cnt * MM / 4, 256, 0, stream>>>(f2 + (size_t)b0 * MM * CC, f2s);
        zero_kernel<<<cnt * MM / 256, 256, 0, stream>>>(KTa);
        gemm_exp_kernel<<<dim3(MM / 128, NN / 128, cnt), 256, 0, stream>>>(f1s, f2s, Ks, KTa);
        bfin_kernel<<<cnt * MM / 256, 256, 0, stream>>>(KTa, bvec);

        for (int it = 0; it < 9; ++it) {
            fused_kernel<<<cnt * 128, 256, 0, stream>>>(Ks, bvec, KTa);
            bfin_kernel<<<cnt * MM / 256, 256, 0, stream>>>(KTa, bvec);
        }

        bp4_kernel<<<cnt * MM / 256, 256, 0, stream>>>(bvec, p2 + (size_t)b0 * MM * 3, bp4);
        final_kernel<<<cnt * NN / 4, 256, 0, stream>>>(Ks, bp4, wc4);
        kabsch_kernel<<<cnt, 256, 0, stream>>>(wc4, p1 + (size_t)b0 * NN * 3, out + (size_t)b0 * 12);
    }

    (void)in_sizes; (void)n_in; (void)out_size;
}

// Round 6
// 1283.980 us; speedup vs baseline: 6.3948x; 6.3948x over previous
//
#include <hip/hip_runtime.h>

#define NB 8
#define NN 4096
#define MM 4096
#define CC 256

typedef unsigned short u16;
typedef __attribute__((ext_vector_type(4))) unsigned short u16x4;
typedef __attribute__((ext_vector_type(8))) short s16x8;
typedef __attribute__((ext_vector_type(4))) float f32x4;

#define INV_EPS 33.333333333333336f
#define POWER   0.94339622641509435f   /* 0.5/(0.5+0.03) */
#define PROB    (1.0f/4096.0f)

static __device__ __forceinline__ float bf2f(u16 h) {
    union { unsigned int u; float f; } v;
    v.u = ((unsigned int)h) << 16;
    return v.f;
}
static __device__ __forceinline__ u16 f2bf(float f) {
    union { float f; unsigned int u; } v;
    v.f = f;
    unsigned int u = v.u;
    u += 0x7fffu + ((u >> 16) & 1u);   // round-to-nearest-even
    return (u16)(u >> 16);
}

// ---------------------------------------------------------------------------
// L2-normalize rows of (rows x 256) fp32 -> bf16. One wave per row.
// ---------------------------------------------------------------------------
__global__ __launch_bounds__(256) void norm_kernel(const float* __restrict__ src,
                                                   u16* __restrict__ dst)
{
    const int t = threadIdx.x, w = t >> 6, lane = t & 63;
    const size_t row = (size_t)blockIdx.x * 4 + w;
    const float* sp = src + row * CC + lane * 4;
    f32x4 v = *(const f32x4*)sp;
    float s = v.x * v.x + v.y * v.y + v.z * v.z + v.w * v.w;
    for (int o = 32; o > 0; o >>= 1) s += __shfl_xor(s, o);
    float rn = rsqrtf(s + 1e-8f);
    u16x4 o4;
    o4.x = f2bf(v.x * rn); o4.y = f2bf(v.y * rn);
    o4.z = f2bf(v.z * rn); o4.w = f2bf(v.w * rn);
    *(u16x4*)(dst + row * CC + lane * 4) = o4;
}

// ---------------------------------------------------------------------------
// zero KTa (d_ws is poisoned 0xAA before every call)
// ---------------------------------------------------------------------------
__global__ __launch_bounds__(256) void zero_kernel(float* __restrict__ KTa)
{
    KTa[blockIdx.x * 256 + threadIdx.x] = 0.f;
}

// ---------------------------------------------------------------------------
// Strip GEMM: Ks[ls][r][c] = exp((f1s[ls][r]·f2s[ls][c] - 1)/eps), bf16 out.
// Epilogue accumulates iteration-1 KTa = PROB * colsum(K) (a0 uniform).
// ---------------------------------------------------------------------------
#define LDSS 72   /* 64 + 8 pad, in u16 units */

__global__ __launch_bounds__(256, 2) void gemm_exp_kernel(
    const u16* __restrict__ f1s, const u16* __restrict__ f2s,
    u16* __restrict__ Ks, float* __restrict__ KTa)
{
    const int t = threadIdx.x;
    const int w = t >> 6, lane = t & 63;
    const int quad = lane >> 4, l15 = lane & 15;
    const int bx = blockIdx.x;   // c-tile (f2 rows)
    const int by = blockIdx.y;   // r-tile (f1 rows)
    const int ls = blockIdx.z;   // local batch in strip

    __shared__ u16 As[128 * LDSS];
    __shared__ u16 Bs[128 * LDSS];
    __shared__ float csum[128];

    if (t < 128) csum[t] = 0.f;   // covered by first loop's __syncthreads

    const u16* f2base = f2s + ((size_t)ls * MM + (size_t)bx * 128) * CC;
    const u16* f1base = f1s + ((size_t)ls * NN + (size_t)by * 128) * CC;

    f32x4 acc[4][4];
#pragma unroll
    for (int i = 0; i < 4; ++i)
#pragma unroll
        for (int j = 0; j < 4; ++j) acc[i][j] = (f32x4){0.f, 0.f, 0.f, 0.f};

    const int g_r = t >> 3;
    const int g_c = (t & 7) << 3;

    for (int kt = 0; kt < 4; ++kt) {
        const int k0 = kt * 64;
        __syncthreads();
#pragma unroll
        for (int i = 0; i < 4; ++i) {
            const int row = g_r + i * 32;
            s16x8 va = *(const s16x8*)(f2base + (size_t)row * CC + k0 + g_c);
            s16x8 vb = *(const s16x8*)(f1base + (size_t)row * CC + k0 + g_c);
            *(s16x8*)&As[row * LDSS + g_c] = va;
            *(s16x8*)&Bs[row * LDSS + g_c] = vb;
        }
        __syncthreads();
#pragma unroll
        for (int s = 0; s < 2; ++s) {
            s16x8 af[4], bfr[4];
#pragma unroll
            for (int i = 0; i < 4; ++i)
                af[i] = *(const s16x8*)&As[((w & 1) * 64 + i * 16 + l15) * LDSS + s * 32 + quad * 8];
#pragma unroll
            for (int j = 0; j < 4; ++j)
                bfr[j] = *(const s16x8*)&Bs[((w >> 1) * 64 + j * 16 + l15) * LDSS + s * 32 + quad * 8];
#pragma unroll
            for (int i = 0; i < 4; ++i)
#pragma unroll
                for (int j = 0; j < 4; ++j)
                    acc[i][j] = __builtin_amdgcn_mfma_f32_16x16x32_bf16(af[i], bfr[j], acc[i][j], 0, 0, 0);
        }
    }

    u16* kb = Ks + (size_t)ls * NN * MM;
    const int rbase = by * 128 + (w >> 1) * 64 + l15;
    const int cbase = bx * 128 + (w & 1) * 64 + quad * 4;
    float part[4][4];
#pragma unroll
    for (int i = 0; i < 4; ++i)
#pragma unroll
        for (int e = 0; e < 4; ++e) part[i][e] = 0.f;

#pragma unroll
    for (int j = 0; j < 4; ++j) {
        const int r = rbase + j * 16;
#pragma unroll
        for (int i = 0; i < 4; ++i) {
            const int c = cbase + i * 16;
            f32x4 v = acc[i][j];
            const float e0 = expf((v.x - 1.f) * INV_EPS);
            const float e1 = expf((v.y - 1.f) * INV_EPS);
            const float e2 = expf((v.z - 1.f) * INV_EPS);
            const float e3 = expf((v.w - 1.f) * INV_EPS);
            u16x4 o;
            o.x = f2bf(e0); o.y = f2bf(e1); o.z = f2bf(e2); o.w = f2bf(e3);
            *(u16x4*)&kb[(size_t)r * MM + c] = o;
            part[i][0] += e0; part[i][1] += e1; part[i][2] += e2; part[i][3] += e3;
        }
    }

#pragma unroll
    for (int i = 0; i < 4; ++i)
#pragma unroll
        for (int e = 0; e < 4; ++e) {
            float v = part[i][e];
            v += __shfl_xor(v, 1); v += __shfl_xor(v, 2);
            v += __shfl_xor(v, 4); v += __shfl_xor(v, 8);
            if (l15 == 0)
                atomicAdd(&csum[(w & 1) * 64 + i * 16 + quad * 4 + e], v);
        }
    __syncthreads();
    if (t < 128)
        atomicAdd(&KTa[(size_t)ls * MM + bx * 128 + t], csum[t] * PROB);
}

// b = (prob2 / (KTa + 1e-8))^power ; re-zero KTa for next fused pass
__global__ __launch_bounds__(256) void bfin_kernel(float* __restrict__ KTa,
                                                   float* __restrict__ bvec)
{
    const int t = blockIdx.x * 256 + threadIdx.x;
    const float v = KTa[t];
    KTa[t] = 0.f;
    bvec[t] = powf(PROB / (v + 1e-8f), POWER);
}

// ---------------------------------------------------------------------------
// FUSED iteration pass (v5): ONE HBM read of K per Sinkhorn iteration.
// Thread t owns columns [16t, 16t+16) EXCLUSIVELY within its block:
//   acc[16] in VGPRs, no atomics, nothing shared in the hot loop.
// Per 4-row batch: phase1 dot partials -> shfl + tiny LDS reduce (2 barriers),
// phase2 re-reads the same 4x8KB rows (L2-resident) and does acc += ar*K.
// Flush: LDS transpose (exclusive plain stores) -> coalesced global atomics.
// grid = cnt*64 (64 rows/block), block = 256.
// ---------------------------------------------------------------------------
__global__ __launch_bounds__(256) void fused_kernel(const u16* __restrict__ Ks,
                                                    const float* __restrict__ bvec,
                                                    float* __restrict__ KTa)
{
    const int t = threadIdx.x, w = t >> 6, lane = t & 63;
    const int ls = blockIdx.x >> 6;
    const int chunk = blockIdx.x & 63;

    __shared__ float wp[4][4];     // [row-in-batch][wave] partial sums
    __shared__ float arr[4];       // per-row a factor
    __shared__ float kacc[4096];   // flush transpose buffer (exclusive)

    // b for this thread's fixed 16 columns -> registers
    const float* bp = bvec + (size_t)ls * MM + t * 16;
    float bv[16];
#pragma unroll
    for (int i = 0; i < 4; ++i) {
        f32x4 b4 = *(const f32x4*)(bp + i * 4);
        bv[i * 4 + 0] = b4.x; bv[i * 4 + 1] = b4.y;
        bv[i * 4 + 2] = b4.z; bv[i * 4 + 3] = b4.w;
    }
    float acc[16];
#pragma unroll
    for (int i = 0; i < 16; ++i) acc[i] = 0.f;

    const u16* kbase = Ks + ((size_t)ls * NN + (size_t)chunk * 64) * MM + t * 16;

    for (int rb = 0; rb < 16; ++rb) {
        const u16* kp = kbase + (size_t)(rb * 4) * MM;

        // phase 1: per-thread dot partials for 4 rows
        float part[4];
#pragma unroll
        for (int r = 0; r < 4; ++r) {
            s16x8 k0 = *(const s16x8*)(kp + (size_t)r * MM);
            s16x8 k1 = *(const s16x8*)(kp + (size_t)r * MM + 8);
            const u16* u0 = (const u16*)&k0;
            const u16* u1 = (const u16*)&k1;
            float s = 0.f;
#pragma unroll
            for (int i = 0; i < 8; ++i) s += bf2f(u0[i]) * bv[i];
#pragma unroll
            for (int i = 0; i < 8; ++i) s += bf2f(u1[i]) * bv[8 + i];
            part[r] = s;
        }
#pragma unroll
        for (int r = 0; r < 4; ++r) {
            float s = part[r];
            for (int o = 32; o > 0; o >>= 1) s += __shfl_xor(s, o);
            if (lane == 0) wp[r][w] = s;
        }
        __syncthreads();
        if (t < 4) {
            const float S = wp[t][0] + wp[t][1] + wp[t][2] + wp[t][3];
            arr[t] = exp2f(POWER * log2f(PROB / (S + 1e-8f)));
        }
        __syncthreads();

        // phase 2: re-read rows (L2-hit) and accumulate ar * K into acc
#pragma unroll
        for (int r = 0; r < 4; ++r) {
            const float ar = arr[r];
            s16x8 k0 = *(const s16x8*)(kp + (size_t)r * MM);
            s16x8 k1 = *(const s16x8*)(kp + (size_t)r * MM + 8);
            const u16* u0 = (const u16*)&k0;
            const u16* u1 = (const u16*)&k1;
#pragma unroll
            for (int i = 0; i < 8; ++i) acc[i]     += ar * bf2f(u0[i]);
#pragma unroll
            for (int i = 0; i < 8; ++i) acc[8 + i] += ar * bf2f(u1[i]);
        }
    }

    // flush: transpose through LDS (exclusive, no atomics), then coalesced
    // global atomics (64 blocks per ls contend, spread in time)
    __syncthreads();
#pragma unroll
    for (int i = 0; i < 4; ++i)
        *(f32x4*)&kacc[t * 16 + i * 4] =
            (f32x4){acc[i * 4 + 0], acc[i * 4 + 1], acc[i * 4 + 2], acc[i * 4 + 3]};
    __syncthreads();
    float* kout = KTa + (size_t)ls * MM;
#pragma unroll
    for (int i = 0; i < 16; ++i)
        atomicAdd(&kout[i * 256 + t], kacc[i * 256 + t]);
}

// bp4[ls][m] = { b, b*p2x, b*p2y, b*p2z }
__global__ __launch_bounds__(256) void bp4_kernel(const float* __restrict__ bvec,
                                                  const float* __restrict__ p2,
                                                  float* __restrict__ bp4)
{
    const int t = blockIdx.x * 256 + threadIdx.x;
    const float bv = bvec[t];
    const float x = p2[(size_t)t * 3 + 0];
    const float y = p2[(size_t)t * 3 + 1];
    const float z = p2[(size_t)t * 3 + 2];
    f32x4 o = {bv, bv * x, bv * y, bv * z};
    *(f32x4*)&bp4[(size_t)t * 4] = o;
}

// ---------------------------------------------------------------------------
// Final pass: per row n, y_k = sum_m K[n][m]*bp4[m][k]; s0 = Kb (final b),
// a_10 derived in-place. wc4 = { corr_x, corr_y, corr_z, weight }.
// ---------------------------------------------------------------------------
__global__ __launch_bounds__(256) void final_kernel(const u16* __restrict__ Ks,
                                                    const float* __restrict__ bp4,
                                                    float* __restrict__ wc4)
{
    const int t = threadIdx.x, w = t >> 6, lane = t & 63;
    const int R = blockIdx.x * 4 + w;
    const int ls = R >> 12, n = R & 4095;
    const u16* kp = Ks + ((size_t)ls * NN + n) * MM + lane * 8;
    const float* pp = bp4 + (size_t)ls * MM * 4;
    float s0 = 0.f, s1 = 0.f, s2 = 0.f, s3 = 0.f;
    for (int pass = 0; pass < 8; ++pass) {
        const int m = pass * 512 + lane * 8;
        s16x8 k8 = *(const s16x8*)(kp + pass * 512);
#pragma unroll
        for (int e = 0; e < 8; ++e) {
            const float kv = bf2f(((const u16*)&k8)[e]);
            f32x4 p = *(const f32x4*)&pp[(size_t)(m + e) * 4];
            s0 += kv * p.x; s1 += kv * p.y; s2 += kv * p.z; s3 += kv * p.w;
        }
    }
    for (int o = 32; o > 0; o >>= 1) {
        s0 += __shfl_xor(s0, o); s1 += __shfl_xor(s1, o);
        s2 += __shfl_xor(s2, o); s3 += __shfl_xor(s3, o);
    }
    if (lane == 0) {
        const float av = powf(PROB / (s0 + 1e-8f), POWER);
        const float wgt = av * s0;
        const float inv = 1.f / (wgt + 1e-8f);
        f32x4 o = {av * s1 * inv, av * s2 * inv, av * s3 * inv, wgt};
        *(f32x4*)&wc4[((size_t)ls * NN + n) * 4] = o;
    }
}

// ---------------------------------------------------------------------------
// Weighted Kabsch per batch: fp64 reduction + one-sided Jacobi SVD (3x3)
// ---------------------------------------------------------------------------
__global__ __launch_bounds__(256) void kabsch_kernel(const float* __restrict__ wc4,
                                                     const float* __restrict__ p1,
                                                     float* __restrict__ out)
{
    const int b = blockIdx.x;
    const int t = threadIdx.x, w = t >> 6, lane = t & 63;
    double acc[16];
#pragma unroll
    for (int k = 0; k < 16; ++k) acc[k] = 0.0;

    for (int n = t; n < NN; n += 256) {
        const float* wp = wc4 + ((size_t)b * NN + n) * 4;
        const float cx = wp[0], cy = wp[1], cz = wp[2], wgt = wp[3];
        const float* pp = p1 + ((size_t)b * NN + n) * 3;
        const double px = pp[0], py = pp[1], pz = pp[2];
        const double wd = wgt;
        const double wcx = wd * cx, wcy = wd * cy, wcz = wd * cz;
        acc[0] += wd;
        acc[1] += wd * px; acc[2] += wd * py; acc[3] += wd * pz;
        acc[4] += wcx;     acc[5] += wcy;     acc[6] += wcz;
        acc[7]  += px * wcx; acc[8]  += px * wcy; acc[9]  += px * wcz;
        acc[10] += py * wcx; acc[11] += py * wcy; acc[12] += py * wcz;
        acc[13] += pz * wcx; acc[14] += pz * wcy; acc[15] += pz * wcz;
    }

    __shared__ double red[4][16];
#pragma unroll
    for (int k = 0; k < 16; ++k) {
        double v = acc[k];
        for (int o = 32; o > 0; o >>= 1) v += __shfl_xor(v, o);
        acc[k] = v;
    }
    if (lane == 0)
        for (int k = 0; k < 16; ++k) red[w][k] = acc[k];
    __syncthreads();

    if (t == 0) {
        double S[16];
        for (int k = 0; k < 16; ++k)
            S[k] = red[0][k] + red[1][k] + red[2][k] + red[3][k];
        const double denom = S[0] + 1e-5;
        const double sfrac = S[0] / denom;
        double ca[3] = {S[1] / denom, S[2] / denom, S[3] / denom};
        double cb[3] = {S[4] / denom, S[5] / denom, S[6] / denom};
        double A[3][3], V[3][3];
        for (int i = 0; i < 3; ++i)
            for (int j = 0; j < 3; ++j) {
                A[i][j] = S[7 + i * 3 + j] / denom - (2.0 - sfrac) * ca[i] * cb[j];
                V[i][j] = (i == j) ? 1.0 : 0.0;
            }
        for (int sweep = 0; sweep < 20; ++sweep) {
            const int PP[3] = {0, 0, 1}, QQ[3] = {1, 2, 2};
            for (int r = 0; r < 3; ++r) {
                const int p = PP[r], q = QQ[r];
                double app = 0, aqq = 0, apq = 0;
                for (int i = 0; i < 3; ++i) {
                    app += A[i][p] * A[i][p];
                    aqq += A[i][q] * A[i][q];
                    apq += A[i][p] * A[i][q];
                }
                if (fabs(apq) < 1e-14 * (app + aqq) + 1e-300) continue;
                const double th = 0.5 * atan2(2.0 * apq, app - aqq);
                const double c = cos(th), sn = sin(th);
                for (int i = 0; i < 3; ++i) {
                    double x = A[i][p], y = A[i][q];
                    A[i][p] = c * x + sn * y; A[i][q] = -sn * x + c * y;
                    x = V[i][p]; y = V[i][q];
                    V[i][p] = c * x + sn * y; V[i][q] = -sn * x + c * y;
                }
            }
        }
        double sv[3];
        for (int j = 0; j < 3; ++j)
            sv[j] = sqrt(A[0][j] * A[0][j] + A[1][j] * A[1][j] + A[2][j] * A[2][j]);
        int idx[3] = {0, 1, 2};
        if (sv[idx[0]] < sv[idx[1]]) { int x = idx[0]; idx[0] = idx[1]; idx[1] = x; }
        if (sv[idx[0]] < sv[idx[2]]) { int x = idx[0]; idx[0] = idx[2]; idx[2] = x; }
        if (sv[idx[1]] < sv[idx[2]]) { int x = idx[1]; idx[1] = idx[2]; idx[2] = x; }
        double U[3][3], Vs[3][3];
        for (int j = 0; j < 3; ++j) {
            const int jj = idx[j];
            const double inv = 1.0 / fmax(sv[jj], 1e-300);
            for (int i = 0; i < 3; ++i) {
                U[i][j] = A[i][jj] * inv;
                Vs[i][j] = V[i][jj];
            }
        }
        double R[3][3];
        for (int i = 0; i < 3; ++i)
            for (int j = 0; j < 3; ++j)
                R[i][j] = Vs[i][0] * U[j][0] + Vs[i][1] * U[j][1] + Vs[i][2] * U[j][2];
        const double det = R[0][0] * (R[1][1] * R[2][2] - R[1][2] * R[2][1])
                         - R[0][1] * (R[1][0] * R[2][2] - R[1][2] * R[2][0])
                         + R[0][2] * (R[1][0] * R[2][1] - R[1][1] * R[2][0]);
        if (det < 0.0) {
            for (int i = 0; i < 3; ++i) Vs[i][2] = -Vs[i][2];
            for (int i = 0; i < 3; ++i)
                for (int j = 0; j < 3; ++j)
                    R[i][j] = Vs[i][0] * U[j][0] + Vs[i][1] * U[j][1] + Vs[i][2] * U[j][2];
        }
        double tr[3];
        for (int i = 0; i < 3; ++i)
            tr[i] = cb[i] - (R[i][0] * ca[0] + R[i][1] * ca[1] + R[i][2] * ca[2]);
        float* o = out + b * 12;
        for (int i = 0; i < 3; ++i) {
            o[i * 4 + 0] = (float)R[i][0];
            o[i * 4 + 1] = (float)R[i][1];
            o[i * 4 + 2] = (float)R[i][2];
            o[i * 4 + 3] = (float)tr[i];
        }
    }
}

// ---------------------------------------------------------------------------
extern "C" void kernel_launch(void* const* d_in, const int* in_sizes, int n_in,
                              void* d_out, int out_size, void* d_ws, size_t ws_size,
                              hipStream_t stream) {
    const float* f1 = (const float*)d_in[0];
    const float* f2 = (const float*)d_in[1];
    const float* p1 = (const float*)d_in[2];
    const float* p2 = (const float*)d_in[3];
    float* out = (float*)d_out;

    const size_t AL = 256;
    const size_t szK   = (size_t)NN * MM * 2;
    const size_t szF1  = (size_t)NN * CC * 2;
    const size_t szF2  = (size_t)MM * CC * 2;
    const size_t szB   = (size_t)MM * 4;
    const size_t szKTa = (size_t)MM * 4;
    const size_t szBp4 = (size_t)MM * 16;
    const size_t szWc4 = (size_t)NN * 16;
    const size_t per_batch = szK + szF1 + szF2 + szB + szKTa + szBp4 + szWc4 + 8 * AL;

    int NS = (int)(ws_size / per_batch);
    if (NS > NB) NS = NB;
    if (NS < 1) NS = 1;

    char* base = (char*)d_ws;
    size_t off = 0;
    auto carve = [&](size_t bytes) -> char* {
        char* p = base + off;
        off += (bytes + AL - 1) & ~(AL - 1);
        return p;
    };
    u16*   Ks   = (u16*)  carve((size_t)NS * szK);
    u16*   f1s  = (u16*)  carve((size_t)NS * szF1);
    u16*   f2s  = (u16*)  carve((size_t)NS * szF2);
    float* bvec = (float*)carve((size_t)NS * szB);
    float* KTa  = (float*)carve((size_t)NS * szKTa);
    float* bp4  = (float*)carve((size_t)NS * szBp4);
    float* wc4  = (float*)carve((size_t)NS * szWc4);

    for (int b0 = 0; b0 < NB; b0 += NS) {
        const int cnt = (NB - b0 < NS) ? (NB - b0) : NS;

        norm_kernel<<<cnt * NN / 4, 256, 0, stream>>>(f1 + (size_t)b0 * NN * CC, f1s);
        norm_kernel<<<cnt * MM / 4, 256, 0, stream>>>(f2 + (size_t)b0 * MM * CC, f2s);
        zero_kernel<<<cnt * MM / 256, 256, 0, stream>>>(KTa);
        gemm_exp_kernel<<<dim3(MM / 128, NN / 128, cnt), 256, 0, stream>>>(f1s, f2s, Ks, KTa);
        bfin_kernel<<<cnt * MM / 256, 256, 0, stream>>>(KTa, bvec);

        for (int it = 0; it < 9; ++it) {
            fused_kernel<<<cnt * 64, 256, 0, stream>>>(Ks, bvec, KTa);
            bfin_kernel<<<cnt * MM / 256, 256, 0, stream>>>(KTa, bvec);
        }

        bp4_kernel<<<cnt * MM / 256, 256, 0, stream>>>(bvec, p2 + (size_t)b0 * MM * 3, bp4);
        final_kernel<<<cnt * NN / 4, 256, 0, stream>>>(Ks, bp4, wc4);
        kabsch_kernel<<<cnt, 256, 0, stream>>>(wc4, p1 + (size_t)b0 * NN * 3, out + (size_t)b0 * 12);
    }

    (void)in_sizes; (void)n_in; (void)out_size;
}

// Round 7
// 1169.487 us; speedup vs baseline: 7.0208x; 1.0979x over previous
//
#include <hip/hip_runtime.h>

#define NB 8
#define NN 4096
#define MM 4096
#define CC 256

typedef unsigned short u16;
typedef __attribute__((ext_vector_type(4))) unsigned short u16x4;
typedef __attribute__((ext_vector_type(8))) short s16x8;
typedef __attribute__((ext_vector_type(4))) float f32x4;

#define INV_EPS 33.333333333333336f
#define POWER   0.94339622641509435f   /* 0.5/(0.5+0.03) */
#define PROB    (1.0f/4096.0f)

static __device__ __forceinline__ float bf2f(u16 h) {
    union { unsigned int u; float f; } v;
    v.u = ((unsigned int)h) << 16;
    return v.f;
}
static __device__ __forceinline__ u16 f2bf(float f) {
    union { float f; unsigned int u; } v;
    v.f = f;
    unsigned int u = v.u;
    u += 0x7fffu + ((u >> 16) & 1u);   // round-to-nearest-even
    return (u16)(u >> 16);
}

// ---------------------------------------------------------------------------
// L2-normalize rows of (rows x 256) fp32 -> bf16. One wave per row.
// ---------------------------------------------------------------------------
__global__ __launch_bounds__(256) void norm_kernel(const float* __restrict__ src,
                                                   u16* __restrict__ dst)
{
    const int t = threadIdx.x, w = t >> 6, lane = t & 63;
    const size_t row = (size_t)blockIdx.x * 4 + w;
    const float* sp = src + row * CC + lane * 4;
    f32x4 v = *(const f32x4*)sp;
    float s = v.x * v.x + v.y * v.y + v.z * v.z + v.w * v.w;
    for (int o = 32; o > 0; o >>= 1) s += __shfl_xor(s, o);
    float rn = rsqrtf(s + 1e-8f);
    u16x4 o4;
    o4.x = f2bf(v.x * rn); o4.y = f2bf(v.y * rn);
    o4.z = f2bf(v.z * rn); o4.w = f2bf(v.w * rn);
    *(u16x4*)(dst + row * CC + lane * 4) = o4;
}

// ---------------------------------------------------------------------------
// zero KTa (d_ws is poisoned 0xAA before every call)
// ---------------------------------------------------------------------------
__global__ __launch_bounds__(256) void zero_kernel(float* __restrict__ KTa)
{
    KTa[blockIdx.x * 256 + threadIdx.x] = 0.f;
}

// ---------------------------------------------------------------------------
// Strip GEMM: Ks[ls][r][c] = exp((f1s[ls][r]·f2s[ls][c] - 1)/eps), bf16 out.
// Epilogue accumulates iteration-1 KTa = PROB * colsum(K) (a0 uniform).
// ---------------------------------------------------------------------------
#define LDSS 72   /* 64 + 8 pad, in u16 units */

__global__ __launch_bounds__(256, 2) void gemm_exp_kernel(
    const u16* __restrict__ f1s, const u16* __restrict__ f2s,
    u16* __restrict__ Ks, float* __restrict__ KTa)
{
    const int t = threadIdx.x;
    const int w = t >> 6, lane = t & 63;
    const int quad = lane >> 4, l15 = lane & 15;
    const int bx = blockIdx.x;   // c-tile (f2 rows)
    const int by = blockIdx.y;   // r-tile (f1 rows)
    const int ls = blockIdx.z;   // local batch in strip

    __shared__ u16 As[128 * LDSS];
    __shared__ u16 Bs[128 * LDSS];
    __shared__ float csum[128];

    if (t < 128) csum[t] = 0.f;   // covered by first loop's __syncthreads

    const u16* f2base = f2s + ((size_t)ls * MM + (size_t)bx * 128) * CC;
    const u16* f1base = f1s + ((size_t)ls * NN + (size_t)by * 128) * CC;

    f32x4 acc[4][4];
#pragma unroll
    for (int i = 0; i < 4; ++i)
#pragma unroll
        for (int j = 0; j < 4; ++j) acc[i][j] = (f32x4){0.f, 0.f, 0.f, 0.f};

    const int g_r = t >> 3;
    const int g_c = (t & 7) << 3;

    for (int kt = 0; kt < 4; ++kt) {
        const int k0 = kt * 64;
        __syncthreads();
#pragma unroll
        for (int i = 0; i < 4; ++i) {
            const int row = g_r + i * 32;
            s16x8 va = *(const s16x8*)(f2base + (size_t)row * CC + k0 + g_c);
            s16x8 vb = *(const s16x8*)(f1base + (size_t)row * CC + k0 + g_c);
            *(s16x8*)&As[row * LDSS + g_c] = va;
            *(s16x8*)&Bs[row * LDSS + g_c] = vb;
        }
        __syncthreads();
#pragma unroll
        for (int s = 0; s < 2; ++s) {
            s16x8 af[4], bfr[4];
#pragma unroll
            for (int i = 0; i < 4; ++i)
                af[i] = *(const s16x8*)&As[((w & 1) * 64 + i * 16 + l15) * LDSS + s * 32 + quad * 8];
#pragma unroll
            for (int j = 0; j < 4; ++j)
                bfr[j] = *(const s16x8*)&Bs[((w >> 1) * 64 + j * 16 + l15) * LDSS + s * 32 + quad * 8];
#pragma unroll
            for (int i = 0; i < 4; ++i)
#pragma unroll
                for (int j = 0; j < 4; ++j)
                    acc[i][j] = __builtin_amdgcn_mfma_f32_16x16x32_bf16(af[i], bfr[j], acc[i][j], 0, 0, 0);
        }
    }

    u16* kb = Ks + (size_t)ls * NN * MM;
    const int rbase = by * 128 + (w >> 1) * 64 + l15;
    const int cbase = bx * 128 + (w & 1) * 64 + quad * 4;
    float part[4][4];
#pragma unroll
    for (int i = 0; i < 4; ++i)
#pragma unroll
        for (int e = 0; e < 4; ++e) part[i][e] = 0.f;

#pragma unroll
    for (int j = 0; j < 4; ++j) {
        const int r = rbase + j * 16;
#pragma unroll
        for (int i = 0; i < 4; ++i) {
            const int c = cbase + i * 16;
            f32x4 v = acc[i][j];
            const float e0 = expf((v.x - 1.f) * INV_EPS);
            const float e1 = expf((v.y - 1.f) * INV_EPS);
            const float e2 = expf((v.z - 1.f) * INV_EPS);
            const float e3 = expf((v.w - 1.f) * INV_EPS);
            u16x4 o;
            o.x = f2bf(e0); o.y = f2bf(e1); o.z = f2bf(e2); o.w = f2bf(e3);
            *(u16x4*)&kb[(size_t)r * MM + c] = o;
            part[i][0] += e0; part[i][1] += e1; part[i][2] += e2; part[i][3] += e3;
        }
    }

#pragma unroll
    for (int i = 0; i < 4; ++i)
#pragma unroll
        for (int e = 0; e < 4; ++e) {
            float v = part[i][e];
            v += __shfl_xor(v, 1); v += __shfl_xor(v, 2);
            v += __shfl_xor(v, 4); v += __shfl_xor(v, 8);
            if (l15 == 0)
                atomicAdd(&csum[(w & 1) * 64 + i * 16 + quad * 4 + e], v);
        }
    __syncthreads();
    if (t < 128)
        atomicAdd(&KTa[(size_t)ls * MM + bx * 128 + t], csum[t] * PROB);
}

// b = (prob2 / (KTa + 1e-8))^power ; re-zero KTa for next fused pass
__global__ __launch_bounds__(256) void bfin_kernel(float* __restrict__ KTa,
                                                   float* __restrict__ bvec)
{
    const int t = blockIdx.x * 256 + threadIdx.x;
    const float v = KTa[t];
    KTa[t] = 0.f;
    bvec[t] = powf(PROB / (v + 1e-8f), POWER);
}

// ---------------------------------------------------------------------------
// FUSED iteration pass (v6): ONE HBM read of K per Sinkhorn iteration.
// Thread t owns columns [16t, 16t+16) EXCLUSIVELY within its block.
// 32 rows/block (grid cnt*128 -> 4 blocks/CU). Per 4-row batch:
//   phase1 dot partials -> shfl -> wp (double-buffered) -> ONE barrier ->
//   every thread redundantly computes ar[4] -> phase2 re-read (L2-resident).
// Flush: LDS transpose (exclusive plain stores) -> coalesced global atomics.
// ---------------------------------------------------------------------------
__global__ __launch_bounds__(256) void fused_kernel(const u16* __restrict__ Ks,
                                                    const float* __restrict__ bvec,
                                                    float* __restrict__ KTa)
{
    const int t = threadIdx.x, w = t >> 6, lane = t & 63;
    const int ls = blockIdx.x >> 7;
    const int chunk = blockIdx.x & 127;

    __shared__ float wp[2][4][4];  // [parity][row-in-batch][wave]
    __shared__ float kacc[4096];   // flush transpose buffer (exclusive)

    // b for this thread's fixed 16 columns -> registers
    const float* bp = bvec + (size_t)ls * MM + t * 16;
    float bv[16];
#pragma unroll
    for (int i = 0; i < 4; ++i) {
        f32x4 b4 = *(const f32x4*)(bp + i * 4);
        bv[i * 4 + 0] = b4.x; bv[i * 4 + 1] = b4.y;
        bv[i * 4 + 2] = b4.z; bv[i * 4 + 3] = b4.w;
    }
    float acc[16];
#pragma unroll
    for (int i = 0; i < 16; ++i) acc[i] = 0.f;

    const u16* kbase = Ks + ((size_t)ls * NN + (size_t)chunk * 32) * MM + t * 16;

    for (int rb = 0; rb < 8; ++rb) {
        const u16* kp = kbase + (size_t)(rb * 4) * MM;
        const int par = rb & 1;

        // phase 1: per-thread dot partials for 4 rows
#pragma unroll
        for (int r = 0; r < 4; ++r) {
            s16x8 k0 = *(const s16x8*)(kp + (size_t)r * MM);
            s16x8 k1 = *(const s16x8*)(kp + (size_t)r * MM + 8);
            const u16* u0 = (const u16*)&k0;
            const u16* u1 = (const u16*)&k1;
            float s = 0.f;
#pragma unroll
            for (int i = 0; i < 8; ++i) s += bf2f(u0[i]) * bv[i];
#pragma unroll
            for (int i = 0; i < 8; ++i) s += bf2f(u1[i]) * bv[8 + i];
            for (int o = 32; o > 0; o >>= 1) s += __shfl_xor(s, o);
            if (lane == 0) wp[par][r][w] = s;
        }
        __syncthreads();

        // every thread computes the 4 row factors (broadcast LDS reads)
        float ar[4];
#pragma unroll
        for (int r = 0; r < 4; ++r) {
            const float S = wp[par][r][0] + wp[par][r][1]
                          + wp[par][r][2] + wp[par][r][3];
            ar[r] = exp2f(POWER * log2f(PROB / (S + 1e-8f)));
        }

        // phase 2: re-read rows (L2/L3-hit) and accumulate ar * K into acc
#pragma unroll
        for (int r = 0; r < 4; ++r) {
            s16x8 k0 = *(const s16x8*)(kp + (size_t)r * MM);
            s16x8 k1 = *(const s16x8*)(kp + (size_t)r * MM + 8);
            const u16* u0 = (const u16*)&k0;
            const u16* u1 = (const u16*)&k1;
#pragma unroll
            for (int i = 0; i < 8; ++i) acc[i]     += ar[r] * bf2f(u0[i]);
#pragma unroll
            for (int i = 0; i < 8; ++i) acc[8 + i] += ar[r] * bf2f(u1[i]);
        }
    }

    // flush: transpose through LDS (exclusive, no atomics), then coalesced
    // global atomics
    __syncthreads();
#pragma unroll
    for (int i = 0; i < 4; ++i)
        *(f32x4*)&kacc[t * 16 + i * 4] =
            (f32x4){acc[i * 4 + 0], acc[i * 4 + 1], acc[i * 4 + 2], acc[i * 4 + 3]};
    __syncthreads();
    float* kout = KTa + (size_t)ls * MM;
#pragma unroll
    for (int i = 0; i < 16; ++i)
        atomicAdd(&kout[i * 256 + t], kacc[i * 256 + t]);
}

// ---------------------------------------------------------------------------
// bp4 PLANAR: bp4[ls][0][m]=b, [1][m]=b*x, [2][m]=b*y, [3][m]=b*z
// ---------------------------------------------------------------------------
__global__ __launch_bounds__(256) void bp4_kernel(const float* __restrict__ bvec,
                                                  const float* __restrict__ p2,
                                                  float* __restrict__ bp4)
{
    const int t = blockIdx.x * 256 + threadIdx.x;   // over cnt*MM
    const int ls = t >> 12;
    const int m = t & 4095;
    const float bv = bvec[t];
    const float x = p2[(size_t)t * 3 + 0];
    const float y = p2[(size_t)t * 3 + 1];
    const float z = p2[(size_t)t * 3 + 2];
    float* pb = bp4 + (size_t)ls * MM * 4;
    pb[m]          = bv;
    pb[MM + m]     = bv * x;
    pb[2 * MM + m] = bv * y;
    pb[3 * MM + m] = bv * z;
}

// ---------------------------------------------------------------------------
// Final pass (v2): planar bp4 staged in LDS (64 KB, loaded once per block),
// 64 rows/block, wave-per-row. Per pass lane l handles 4 cols (conflict-free
// ds_read_b128 x4 + coalesced u16x4 K load). s0 = Kb -> a_10 derived here.
// wc4 = { corr_x, corr_y, corr_z, weight }. grid = cnt*64.
// ---------------------------------------------------------------------------
__global__ __launch_bounds__(256) void final_kernel(const u16* __restrict__ Ks,
                                                    const float* __restrict__ bp4,
                                                    float* __restrict__ wc4)
{
    __shared__ float planes[4][4096];   // exactly 64 KB
    const int t = threadIdx.x, w = t >> 6, lane = t & 63;
    const int ls = blockIdx.x >> 6;
    const int chunk = blockIdx.x & 63;

    const float* pb = bp4 + (size_t)ls * MM * 4;
#pragma unroll
    for (int p = 0; p < 4; ++p)
#pragma unroll
        for (int i = 0; i < 4; ++i) {
            const int idx = i * 1024 + t * 4;
            *(f32x4*)&planes[p][idx] = *(const f32x4*)(pb + p * MM + idx);
        }
    __syncthreads();

    for (int rr = 0; rr < 16; ++rr) {
        const int n = chunk * 64 + rr * 4 + w;
        const u16* kp = Ks + ((size_t)ls * NN + n) * MM;
        float s0 = 0.f, s1 = 0.f, s2 = 0.f, s3 = 0.f;
#pragma unroll 4
        for (int pass = 0; pass < 16; ++pass) {
            const int m = pass * 256 + lane * 4;
            u16x4 k4 = *(const u16x4*)(kp + m);
            f32x4 p0 = *(const f32x4*)&planes[0][m];
            f32x4 p1 = *(const f32x4*)&planes[1][m];
            f32x4 p2v = *(const f32x4*)&planes[2][m];
            f32x4 p3 = *(const f32x4*)&planes[3][m];
            const float k0 = bf2f(k4.x), k1 = bf2f(k4.y);
            const float k2 = bf2f(k4.z), k3 = bf2f(k4.w);
            s0 += k0 * p0.x + k1 * p0.y + k2 * p0.z + k3 * p0.w;
            s1 += k0 * p1.x + k1 * p1.y + k2 * p1.z + k3 * p1.w;
            s2 += k0 * p2v.x + k1 * p2v.y + k2 * p2v.z + k3 * p2v.w;
            s3 += k0 * p3.x + k1 * p3.y + k2 * p3.z + k3 * p3.w;
        }
        for (int o = 32; o > 0; o >>= 1) {
            s0 += __shfl_xor(s0, o); s1 += __shfl_xor(s1, o);
            s2 += __shfl_xor(s2, o); s3 += __shfl_xor(s3, o);
        }
        if (lane == 0) {
            const float av = powf(PROB / (s0 + 1e-8f), POWER);
            const float wgt = av * s0;
            const float inv = 1.f / (wgt + 1e-8f);
            f32x4 o = {av * s1 * inv, av * s2 * inv, av * s3 * inv, wgt};
            *(f32x4*)&wc4[((size_t)ls * NN + n) * 4] = o;
        }
    }
}

// ---------------------------------------------------------------------------
// Weighted Kabsch per batch: fp64 reduction + one-sided Jacobi SVD (3x3)
// ---------------------------------------------------------------------------
__global__ __launch_bounds__(256) void kabsch_kernel(const float* __restrict__ wc4,
                                                     const float* __restrict__ p1,
                                                     float* __restrict__ out)
{
    const int b = blockIdx.x;
    const int t = threadIdx.x, w = t >> 6, lane = t & 63;
    double acc[16];
#pragma unroll
    for (int k = 0; k < 16; ++k) acc[k] = 0.0;

    for (int n = t; n < NN; n += 256) {
        const float* wp = wc4 + ((size_t)b * NN + n) * 4;
        const float cx = wp[0], cy = wp[1], cz = wp[2], wgt = wp[3];
        const float* pp = p1 + ((size_t)b * NN + n) * 3;
        const double px = pp[0], py = pp[1], pz = pp[2];
        const double wd = wgt;
        const double wcx = wd * cx, wcy = wd * cy, wcz = wd * cz;
        acc[0] += wd;
        acc[1] += wd * px; acc[2] += wd * py; acc[3] += wd * pz;
        acc[4] += wcx;     acc[5] += wcy;     acc[6] += wcz;
        acc[7]  += px * wcx; acc[8]  += px * wcy; acc[9]  += px * wcz;
        acc[10] += py * wcx; acc[11] += py * wcy; acc[12] += py * wcz;
        acc[13] += pz * wcx; acc[14] += pz * wcy; acc[15] += pz * wcz;
    }

    __shared__ double red[4][16];
#pragma unroll
    for (int k = 0; k < 16; ++k) {
        double v = acc[k];
        for (int o = 32; o > 0; o >>= 1) v += __shfl_xor(v, o);
        acc[k] = v;
    }
    if (lane == 0)
        for (int k = 0; k < 16; ++k) red[w][k] = acc[k];
    __syncthreads();

    if (t == 0) {
        double S[16];
        for (int k = 0; k < 16; ++k)
            S[k] = red[0][k] + red[1][k] + red[2][k] + red[3][k];
        const double denom = S[0] + 1e-5;
        const double sfrac = S[0] / denom;
        double ca[3] = {S[1] / denom, S[2] / denom, S[3] / denom};
        double cb[3] = {S[4] / denom, S[5] / denom, S[6] / denom};
        double A[3][3], V[3][3];
        for (int i = 0; i < 3; ++i)
            for (int j = 0; j < 3; ++j) {
                A[i][j] = S[7 + i * 3 + j] / denom - (2.0 - sfrac) * ca[i] * cb[j];
                V[i][j] = (i == j) ? 1.0 : 0.0;
            }
        for (int sweep = 0; sweep < 20; ++sweep) {
            const int PP[3] = {0, 0, 1}, QQ[3] = {1, 2, 2};
            for (int r = 0; r < 3; ++r) {
                const int p = PP[r], q = QQ[r];
                double app = 0, aqq = 0, apq = 0;
                for (int i = 0; i < 3; ++i) {
                    app += A[i][p] * A[i][p];
                    aqq += A[i][q] * A[i][q];
                    apq += A[i][p] * A[i][q];
                }
                if (fabs(apq) < 1e-14 * (app + aqq) + 1e-300) continue;
                const double th = 0.5 * atan2(2.0 * apq, app - aqq);
                const double c = cos(th), sn = sin(th);
                for (int i = 0; i < 3; ++i) {
                    double x = A[i][p], y = A[i][q];
                    A[i][p] = c * x + sn * y; A[i][q] = -sn * x + c * y;
                    x = V[i][p]; y = V[i][q];
                    V[i][p] = c * x + sn * y; V[i][q] = -sn * x + c * y;
                }
            }
        }
        double sv[3];
        for (int j = 0; j < 3; ++j)
            sv[j] = sqrt(A[0][j] * A[0][j] + A[1][j] * A[1][j] + A[2][j] * A[2][j]);
        int idx[3] = {0, 1, 2};
        if (sv[idx[0]] < sv[idx[1]]) { int x = idx[0]; idx[0] = idx[1]; idx[1] = x; }
        if (sv[idx[0]] < sv[idx[2]]) { int x = idx[0]; idx[0] = idx[2]; idx[2] = x; }
        if (sv[idx[1]] < sv[idx[2]]) { int x = idx[1]; idx[1] = idx[2]; idx[2] = x; }
        double U[3][3], Vs[3][3];
        for (int j = 0; j < 3; ++j) {
            const int jj = idx[j];
            const double inv = 1.0 / fmax(sv[jj], 1e-300);
            for (int i = 0; i < 3; ++i) {
                U[i][j] = A[i][jj] * inv;
                Vs[i][j] = V[i][jj];
            }
        }
        double R[3][3];
        for (int i = 0; i < 3; ++i)
            for (int j = 0; j < 3; ++j)
                R[i][j] = Vs[i][0] * U[j][0] + Vs[i][1] * U[j][1] + Vs[i][2] * U[j][2];
        const double det = R[0][0] * (R[1][1] * R[2][2] - R[1][2] * R[2][1])
                         - R[0][1] * (R[1][0] * R[2][2] - R[1][2] * R[2][0])
                         + R[0][2] * (R[1][0] * R[2][1] - R[1][1] * R[2][0]);
        if (det < 0.0) {
            for (int i = 0; i < 3; ++i) Vs[i][2] = -Vs[i][2];
            for (int i = 0; i < 3; ++i)
                for (int j = 0; j < 3; ++j)
                    R[i][j] = Vs[i][0] * U[j][0] + Vs[i][1] * U[j][1] + Vs[i][2] * U[j][2];
        }
        double tr[3];
        for (int i = 0; i < 3; ++i)
            tr[i] = cb[i] - (R[i][0] * ca[0] + R[i][1] * ca[1] + R[i][2] * ca[2]);
        float* o = out + b * 12;
        for (int i = 0; i < 3; ++i) {
            o[i * 4 + 0] = (float)R[i][0];
            o[i * 4 + 1] = (float)R[i][1];
            o[i * 4 + 2] = (float)R[i][2];
            o[i * 4 + 3] = (float)tr[i];
        }
    }
}

// ---------------------------------------------------------------------------
extern "C" void kernel_launch(void* const* d_in, const int* in_sizes, int n_in,
                              void* d_out, int out_size, void* d_ws, size_t ws_size,
                              hipStream_t stream) {
    const float* f1 = (const float*)d_in[0];
    const float* f2 = (const float*)d_in[1];
    const float* p1 = (const float*)d_in[2];
    const float* p2 = (const float*)d_in[3];
    float* out = (float*)d_out;

    const size_t AL = 256;
    const size_t szK   = (size_t)NN * MM * 2;
    const size_t szF1  = (size_t)NN * CC * 2;
    const size_t szF2  = (size_t)MM * CC * 2;
    const size_t szB   = (size_t)MM * 4;
    const size_t szKTa = (size_t)MM * 4;
    const size_t szBp4 = (size_t)MM * 16;
    const size_t szWc4 = (size_t)NN * 16;
    const size_t per_batch = szK + szF1 + szF2 + szB + szKTa + szBp4 + szWc4 + 8 * AL;

    int NS = (int)(ws_size / per_batch);
    if (NS > NB) NS = NB;
    if (NS < 1) NS = 1;

    char* base = (char*)d_ws;
    size_t off = 0;
    auto carve = [&](size_t bytes) -> char* {
        char* p = base + off;
        off += (bytes + AL - 1) & ~(AL - 1);
        return p;
    };
    u16*   Ks   = (u16*)  carve((size_t)NS * szK);
    u16*   f1s  = (u16*)  carve((size_t)NS * szF1);
    u16*   f2s  = (u16*)  carve((size_t)NS * szF2);
    float* bvec = (float*)carve((size_t)NS * szB);
    float* KTa  = (float*)carve((size_t)NS * szKTa);
    float* bp4  = (float*)carve((size_t)NS * szBp4);
    float* wc4  = (float*)carve((size_t)NS * szWc4);

    for (int b0 = 0; b0 < NB; b0 += NS) {
        const int cnt = (NB - b0 < NS) ? (NB - b0) : NS;

        norm_kernel<<<cnt * NN / 4, 256, 0, stream>>>(f1 + (size_t)b0 * NN * CC, f1s);
        norm_kernel<<<cnt * MM / 4, 256, 0, stream>>>(f2 + (size_t)b0 * MM * CC, f2s);
        zero_kernel<<<cnt * MM / 256, 256, 0, stream>>>(KTa);
        gemm_exp_kernel<<<dim3(MM / 128, NN / 128, cnt), 256, 0, stream>>>(f1s, f2s, Ks, KTa);
        bfin_kernel<<<cnt * MM / 256, 256, 0, stream>>>(KTa, bvec);

        for (int it = 0; it < 9; ++it) {
            fused_kernel<<<cnt * 128, 256, 0, stream>>>(Ks, bvec, KTa);
            bfin_kernel<<<cnt * MM / 256, 256, 0, stream>>>(KTa, bvec);
        }

        bp4_kernel<<<cnt * MM / 256, 256, 0, stream>>>(bvec, p2 + (size_t)b0 * MM * 3, bp4);
        final_kernel<<<cnt * 64, 256, 0, stream>>>(Ks, bp4, wc4);
        kabsch_kernel<<<cnt, 256, 0, stream>>>(wc4, p1 + (size_t)b0 * NN * 3, out + (size_t)b0 * 12);
    }

    (void)in_sizes; (void)n_in; (void)out_size;
}

// Round 8
// 1028.728 us; speedup vs baseline: 7.9815x; 1.1368x over previous
//
#include <hip/hip_runtime.h>

#define NB 8
#define NN 4096
#define MM 4096
#define CC 256

typedef unsigned short u16;
typedef __attribute__((ext_vector_type(4))) unsigned short u16x4;
typedef __attribute__((ext_vector_type(8))) short s16x8;
typedef __attribute__((ext_vector_type(4))) float f32x4;

#define INV_EPS 33.333333333333336f
#define EXP2_SCALE 48.089834696296504f   /* INV_EPS / ln(2) */
#define POWER   0.94339622641509435f     /* 0.5/(0.5+0.03) */
#define PROB    (1.0f/4096.0f)

static __device__ __forceinline__ float bf2f(u16 h) {
    union { unsigned int u; float f; } v;
    v.u = ((unsigned int)h) << 16;
    return v.f;
}
static __device__ __forceinline__ u16 f2bf(float f) {
    union { float f; unsigned int u; } v;
    v.f = f;
    unsigned int u = v.u;
    u += 0x7fffu + ((u >> 16) & 1u);   // round-to-nearest-even
    return (u16)(u >> 16);
}
static __device__ __forceinline__ float gfun(float x) {
    // (PROB / (x + 1e-8))^POWER, x > 0
    return exp2f(POWER * log2f(PROB / (x + 1e-8f)));
}

// ---------------------------------------------------------------------------
// L2-normalize rows of (rows x 256) fp32 -> bf16. One wave per row.
// ---------------------------------------------------------------------------
__global__ __launch_bounds__(256) void norm_kernel(const float* __restrict__ src,
                                                   u16* __restrict__ dst)
{
    const int t = threadIdx.x, w = t >> 6, lane = t & 63;
    const size_t row = (size_t)blockIdx.x * 4 + w;
    const float* sp = src + row * CC + lane * 4;
    f32x4 v = *(const f32x4*)sp;
    float s = v.x * v.x + v.y * v.y + v.z * v.z + v.w * v.w;
    for (int o = 32; o > 0; o >>= 1) s += __shfl_xor(s, o);
    float rn = rsqrtf(s + 1e-8f);
    u16x4 o4;
    o4.x = f2bf(v.x * rn); o4.y = f2bf(v.y * rn);
    o4.z = f2bf(v.z * rn); o4.w = f2bf(v.w * rn);
    *(u16x4*)(dst + row * CC + lane * 4) = o4;
}

// ---------------------------------------------------------------------------
// zero KTa (d_ws is poisoned 0xAA before every call)
// ---------------------------------------------------------------------------
__global__ __launch_bounds__(256) void zero_kernel(float* __restrict__ KTa)
{
    KTa[blockIdx.x * 256 + threadIdx.x] = 0.f;
}

// ---------------------------------------------------------------------------
// Strip GEMM: Ks[ls][r][c] = exp((f1s[ls][r]·f2s[ls][c] - 1)/eps), bf16 out.
// Epilogue accumulates iteration-1 KTa = PROB * colsum(K) (a0 uniform).
// Colsum uses per-wave private LDS regions (NO LDS atomics - CAS on gfx950).
// ---------------------------------------------------------------------------
#define LDSS 72   /* 64 + 8 pad, in u16 units */

__global__ __launch_bounds__(256, 3) void gemm_exp_kernel(
    const u16* __restrict__ f1s, const u16* __restrict__ f2s,
    u16* __restrict__ Ks, float* __restrict__ KTa)
{
    const int t = threadIdx.x;
    const int w = t >> 6, lane = t & 63;
    const int quad = lane >> 4, l15 = lane & 15;
    const int bx = blockIdx.x;   // c-tile (f2 rows)
    const int by = blockIdx.y;   // r-tile (f1 rows)
    const int ls = blockIdx.z;   // local batch in strip

    __shared__ u16 As[128 * LDSS];
    __shared__ u16 Bs[128 * LDSS];
    __shared__ float csum4[4][64];   // per-wave colsum partials (no atomics)

    csum4[w][lane] = 0.f;   // covered by first loop's __syncthreads

    const u16* f2base = f2s + ((size_t)ls * MM + (size_t)bx * 128) * CC;
    const u16* f1base = f1s + ((size_t)ls * NN + (size_t)by * 128) * CC;

    f32x4 acc[4][4];
#pragma unroll
    for (int i = 0; i < 4; ++i)
#pragma unroll
        for (int j = 0; j < 4; ++j) acc[i][j] = (f32x4){0.f, 0.f, 0.f, 0.f};

    const int g_r = t >> 3;
    const int g_c = (t & 7) << 3;

    for (int kt = 0; kt < 4; ++kt) {
        const int k0 = kt * 64;
        __syncthreads();
#pragma unroll
        for (int i = 0; i < 4; ++i) {
            const int row = g_r + i * 32;
            s16x8 va = *(const s16x8*)(f2base + (size_t)row * CC + k0 + g_c);
            s16x8 vb = *(const s16x8*)(f1base + (size_t)row * CC + k0 + g_c);
            *(s16x8*)&As[row * LDSS + g_c] = va;
            *(s16x8*)&Bs[row * LDSS + g_c] = vb;
        }
        __syncthreads();
#pragma unroll
        for (int s = 0; s < 2; ++s) {
            s16x8 af[4], bfr[4];
#pragma unroll
            for (int i = 0; i < 4; ++i)
                af[i] = *(const s16x8*)&As[((w & 1) * 64 + i * 16 + l15) * LDSS + s * 32 + quad * 8];
#pragma unroll
            for (int j = 0; j < 4; ++j)
                bfr[j] = *(const s16x8*)&Bs[((w >> 1) * 64 + j * 16 + l15) * LDSS + s * 32 + quad * 8];
#pragma unroll
            for (int i = 0; i < 4; ++i)
#pragma unroll
                for (int j = 0; j < 4; ++j)
                    acc[i][j] = __builtin_amdgcn_mfma_f32_16x16x32_bf16(af[i], bfr[j], acc[i][j], 0, 0, 0);
        }
    }

    u16* kb = Ks + (size_t)ls * NN * MM;
    const int rbase = by * 128 + (w >> 1) * 64 + l15;
    const int cbase = bx * 128 + (w & 1) * 64 + quad * 4;
    float part[4][4];
#pragma unroll
    for (int i = 0; i < 4; ++i)
#pragma unroll
        for (int e = 0; e < 4; ++e) part[i][e] = 0.f;

#pragma unroll
    for (int j = 0; j < 4; ++j) {
        const int r = rbase + j * 16;
#pragma unroll
        for (int i = 0; i < 4; ++i) {
            const int c = cbase + i * 16;
            f32x4 v = acc[i][j];
            const float e0 = exp2f((v.x - 1.f) * EXP2_SCALE);
            const float e1 = exp2f((v.y - 1.f) * EXP2_SCALE);
            const float e2 = exp2f((v.z - 1.f) * EXP2_SCALE);
            const float e3 = exp2f((v.w - 1.f) * EXP2_SCALE);
            u16x4 o;
            o.x = f2bf(e0); o.y = f2bf(e1); o.z = f2bf(e2); o.w = f2bf(e3);
            *(u16x4*)&kb[(size_t)r * MM + c] = o;
            part[i][0] += e0; part[i][1] += e1; part[i][2] += e2; part[i][3] += e3;
        }
    }

    // reduce colsums over the 16 l15 lanes of each quad; plain += into the
    // wave-private region (active lanes hit distinct addresses -> no race)
#pragma unroll
    for (int i = 0; i < 4; ++i)
#pragma unroll
        for (int e = 0; e < 4; ++e) {
            float v = part[i][e];
            v += __shfl_xor(v, 1); v += __shfl_xor(v, 2);
            v += __shfl_xor(v, 4); v += __shfl_xor(v, 8);
            if (l15 == 0)
                csum4[w][i * 16 + quad * 4 + e] += v;
        }
    __syncthreads();
    if (t < 128) {
        const int half = t >> 6, local = t & 63;
        const float v = csum4[half][local] + csum4[half + 2][local];
        atomicAdd(&KTa[(size_t)ls * MM + bx * 128 + t], v * PROB);
    }
}

// b = (prob2 / (KTa + 1e-8))^power ; re-zero KTa for next fused pass
__global__ __launch_bounds__(256) void bfin_kernel(float* __restrict__ KTa,
                                                   float* __restrict__ bvec)
{
    const int t = blockIdx.x * 256 + threadIdx.x;
    const float v = KTa[t];
    KTa[t] = 0.f;
    bvec[t] = gfun(v);
}

// ---------------------------------------------------------------------------
// FUSED iteration pass (v7): ONE read of K per Sinkhorn iteration, and the
// packed bf16 row data is KEPT IN REGISTERS across the barrier (kv[4][2],
// 32 VGPRs) -> phase 2 has zero memory traffic.
// Thread t owns columns [16t, 16t+16) EXCLUSIVELY within its block.
// 32 rows/block (grid cnt*128 -> 4 blocks/CU). One barrier per 4-row batch
// (wp double-buffered; every thread redundantly computes ar[4]).
// Flush: LDS transpose (exclusive plain stores) -> coalesced global atomics.
// ---------------------------------------------------------------------------
__global__ __launch_bounds__(256) void fused_kernel(const u16* __restrict__ Ks,
                                                    const float* __restrict__ bvec,
                                                    float* __restrict__ KTa)
{
    const int t = threadIdx.x, w = t >> 6, lane = t & 63;
    const int ls = blockIdx.x >> 7;
    const int chunk = blockIdx.x & 127;

    __shared__ float wp[2][4][4];  // [parity][row-in-batch][wave]
    __shared__ float kacc[4096];   // flush transpose buffer (exclusive)

    // b for this thread's fixed 16 columns -> registers
    const float* bp = bvec + (size_t)ls * MM + t * 16;
    float bv[16];
#pragma unroll
    for (int i = 0; i < 4; ++i) {
        f32x4 b4 = *(const f32x4*)(bp + i * 4);
        bv[i * 4 + 0] = b4.x; bv[i * 4 + 1] = b4.y;
        bv[i * 4 + 2] = b4.z; bv[i * 4 + 3] = b4.w;
    }
    float acc[16];
#pragma unroll
    for (int i = 0; i < 16; ++i) acc[i] = 0.f;

    const u16* kbase = Ks + ((size_t)ls * NN + (size_t)chunk * 32) * MM + t * 16;

    for (int rb = 0; rb < 8; ++rb) {
        const u16* kp = kbase + (size_t)(rb * 4) * MM;
        const int par = rb & 1;

        // phase 1: load 4 rows (kept packed in regs), dot partials, reduce
        s16x8 kv[4][2];
#pragma unroll
        for (int r = 0; r < 4; ++r) {
            kv[r][0] = *(const s16x8*)(kp + (size_t)r * MM);
            kv[r][1] = *(const s16x8*)(kp + (size_t)r * MM + 8);
        }
#pragma unroll
        for (int r = 0; r < 4; ++r) {
            const u16* u0 = (const u16*)&kv[r][0];
            const u16* u1 = (const u16*)&kv[r][1];
            float s = 0.f;
#pragma unroll
            for (int i = 0; i < 8; ++i) s += bf2f(u0[i]) * bv[i];
#pragma unroll
            for (int i = 0; i < 8; ++i) s += bf2f(u1[i]) * bv[8 + i];
            for (int o = 32; o > 0; o >>= 1) s += __shfl_xor(s, o);
            if (lane == 0) wp[par][r][w] = s;
        }
        __syncthreads();

        // every thread computes the 4 row factors (broadcast LDS reads)
        float ar[4];
#pragma unroll
        for (int r = 0; r < 4; ++r) {
            const float S = wp[par][r][0] + wp[par][r][1]
                          + wp[par][r][2] + wp[par][r][3];
            ar[r] = gfun(S);
        }

        // phase 2: accumulate ar * K from the register-held rows (no loads)
#pragma unroll
        for (int r = 0; r < 4; ++r) {
            const u16* u0 = (const u16*)&kv[r][0];
            const u16* u1 = (const u16*)&kv[r][1];
#pragma unroll
            for (int i = 0; i < 8; ++i) acc[i]     += ar[r] * bf2f(u0[i]);
#pragma unroll
            for (int i = 0; i < 8; ++i) acc[8 + i] += ar[r] * bf2f(u1[i]);
        }
    }

    // flush: transpose through LDS (exclusive, no atomics), then coalesced
    // global atomics
    __syncthreads();
#pragma unroll
    for (int i = 0; i < 4; ++i)
        *(f32x4*)&kacc[t * 16 + i * 4] =
            (f32x4){acc[i * 4 + 0], acc[i * 4 + 1], acc[i * 4 + 2], acc[i * 4 + 3]};
    __syncthreads();
    float* kout = KTa + (size_t)ls * MM;
#pragma unroll
    for (int i = 0; i < 16; ++i)
        atomicAdd(&kout[i * 256 + t], kacc[i * 256 + t]);
}

// ---------------------------------------------------------------------------
// bp4 PLANAR: bp4[ls][0][m]=b, [1][m]=b*x, [2][m]=b*y, [3][m]=b*z
// ---------------------------------------------------------------------------
__global__ __launch_bounds__(256) void bp4_kernel(const float* __restrict__ bvec,
                                                  const float* __restrict__ p2,
                                                  float* __restrict__ bp4)
{
    const int t = blockIdx.x * 256 + threadIdx.x;   // over cnt*MM
    const int ls = t >> 12;
    const int m = t & 4095;
    const float bv = bvec[t];
    const float x = p2[(size_t)t * 3 + 0];
    const float y = p2[(size_t)t * 3 + 1];
    const float z = p2[(size_t)t * 3 + 2];
    float* pb = bp4 + (size_t)ls * MM * 4;
    pb[m]          = bv;
    pb[MM + m]     = bv * x;
    pb[2 * MM + m] = bv * y;
    pb[3 * MM + m] = bv * z;
}

// ---------------------------------------------------------------------------
// Final pass: planar bp4 staged in LDS (64 KB, loaded once per block),
// 64 rows/block, wave-per-row. s0 = Kb -> a_10 derived here.
// wc4 = { corr_x, corr_y, corr_z, weight }. grid = cnt*64.
// ---------------------------------------------------------------------------
__global__ __launch_bounds__(256) void final_kernel(const u16* __restrict__ Ks,
                                                    const float* __restrict__ bp4,
                                                    float* __restrict__ wc4)
{
    __shared__ float planes[4][4096];   // exactly 64 KB
    const int t = threadIdx.x, w = t >> 6, lane = t & 63;
    const int ls = blockIdx.x >> 6;
    const int chunk = blockIdx.x & 63;

    const float* pb = bp4 + (size_t)ls * MM * 4;
#pragma unroll
    for (int p = 0; p < 4; ++p)
#pragma unroll
        for (int i = 0; i < 4; ++i) {
            const int idx = i * 1024 + t * 4;
            *(f32x4*)&planes[p][idx] = *(const f32x4*)(pb + p * MM + idx);
        }
    __syncthreads();

    for (int rr = 0; rr < 16; ++rr) {
        const int n = chunk * 64 + rr * 4 + w;
        const u16* kp = Ks + ((size_t)ls * NN + n) * MM;
        float s0 = 0.f, s1 = 0.f, s2 = 0.f, s3 = 0.f;
#pragma unroll 4
        for (int pass = 0; pass < 16; ++pass) {
            const int m = pass * 256 + lane * 4;
            u16x4 k4 = *(const u16x4*)(kp + m);
            f32x4 p0 = *(const f32x4*)&planes[0][m];
            f32x4 p1 = *(const f32x4*)&planes[1][m];
            f32x4 p2v = *(const f32x4*)&planes[2][m];
            f32x4 p3 = *(const f32x4*)&planes[3][m];
            const float k0 = bf2f(k4.x), k1 = bf2f(k4.y);
            const float k2 = bf2f(k4.z), k3 = bf2f(k4.w);
            s0 += k0 * p0.x + k1 * p0.y + k2 * p0.z + k3 * p0.w;
            s1 += k0 * p1.x + k1 * p1.y + k2 * p1.z + k3 * p1.w;
            s2 += k0 * p2v.x + k1 * p2v.y + k2 * p2v.z + k3 * p2v.w;
            s3 += k0 * p3.x + k1 * p3.y + k2 * p3.z + k3 * p3.w;
        }
        for (int o = 32; o > 0; o >>= 1) {
            s0 += __shfl_xor(s0, o); s1 += __shfl_xor(s1, o);
            s2 += __shfl_xor(s2, o); s3 += __shfl_xor(s3, o);
        }
        if (lane == 0) {
            const float av = gfun(s0);
            const float wgt = av * s0;
            const float inv = 1.f / (wgt + 1e-8f);
            f32x4 o = {av * s1 * inv, av * s2 * inv, av * s3 * inv, wgt};
            *(f32x4*)&wc4[((size_t)ls * NN + n) * 4] = o;
        }
    }
}

// ---------------------------------------------------------------------------
// Weighted Kabsch per batch: fp64 reduction + one-sided Jacobi SVD (3x3)
// ---------------------------------------------------------------------------
__global__ __launch_bounds__(256) void kabsch_kernel(const float* __restrict__ wc4,
                                                     const float* __restrict__ p1,
                                                     float* __restrict__ out)
{
    const int b = blockIdx.x;
    const int t = threadIdx.x, w = t >> 6, lane = t & 63;
    double acc[16];
#pragma unroll
    for (int k = 0; k < 16; ++k) acc[k] = 0.0;

    for (int n = t; n < NN; n += 256) {
        const float* wp = wc4 + ((size_t)b * NN + n) * 4;
        const float cx = wp[0], cy = wp[1], cz = wp[2], wgt = wp[3];
        const float* pp = p1 + ((size_t)b * NN + n) * 3;
        const double px = pp[0], py = pp[1], pz = pp[2];
        const double wd = wgt;
        const double wcx = wd * cx, wcy = wd * cy, wcz = wd * cz;
        acc[0] += wd;
        acc[1] += wd * px; acc[2] += wd * py; acc[3] += wd * pz;
        acc[4] += wcx;     acc[5] += wcy;     acc[6] += wcz;
        acc[7]  += px * wcx; acc[8]  += px * wcy; acc[9]  += px * wcz;
        acc[10] += py * wcx; acc[11] += py * wcy; acc[12] += py * wcz;
        acc[13] += pz * wcx; acc[14] += pz * wcy; acc[15] += pz * wcz;
    }

    __shared__ double red[4][16];
#pragma unroll
    for (int k = 0; k < 16; ++k) {
        double v = acc[k];
        for (int o = 32; o > 0; o >>= 1) v += __shfl_xor(v, o);
        acc[k] = v;
    }
    if (lane == 0)
        for (int k = 0; k < 16; ++k) red[w][k] = acc[k];
    __syncthreads();

    if (t == 0) {
        double S[16];
        for (int k = 0; k < 16; ++k)
            S[k] = red[0][k] + red[1][k] + red[2][k] + red[3][k];
        const double denom = S[0] + 1e-5;
        const double sfrac = S[0] / denom;
        double ca[3] = {S[1] / denom, S[2] / denom, S[3] / denom};
        double cb[3] = {S[4] / denom, S[5] / denom, S[6] / denom};
        double A[3][3], V[3][3];
        for (int i = 0; i < 3; ++i)
            for (int j = 0; j < 3; ++j) {
                A[i][j] = S[7 + i * 3 + j] / denom - (2.0 - sfrac) * ca[i] * cb[j];
                V[i][j] = (i == j) ? 1.0 : 0.0;
            }
        for (int sweep = 0; sweep < 20; ++sweep) {
            const int PP[3] = {0, 0, 1}, QQ[3] = {1, 2, 2};
            for (int r = 0; r < 3; ++r) {
                const int p = PP[r], q = QQ[r];
                double app = 0, aqq = 0, apq = 0;
                for (int i = 0; i < 3; ++i) {
                    app += A[i][p] * A[i][p];
                    aqq += A[i][q] * A[i][q];
                    apq += A[i][p] * A[i][q];
                }
                if (fabs(apq) < 1e-14 * (app + aqq) + 1e-300) continue;
                const double th = 0.5 * atan2(2.0 * apq, app - aqq);
                const double c = cos(th), sn = sin(th);
                for (int i = 0; i < 3; ++i) {
                    double x = A[i][p], y = A[i][q];
                    A[i][p] = c * x + sn * y; A[i][q] = -sn * x + c * y;
                    x = V[i][p]; y = V[i][q];
                    V[i][p] = c * x + sn * y; V[i][q] = -sn * x + c * y;
                }
            }
        }
        double sv[3];
        for (int j = 0; j < 3; ++j)
            sv[j] = sqrt(A[0][j] * A[0][j] + A[1][j] * A[1][j] + A[2][j] * A[2][j]);
        int idx[3] = {0, 1, 2};
        if (sv[idx[0]] < sv[idx[1]]) { int x = idx[0]; idx[0] = idx[1]; idx[1] = x; }
        if (sv[idx[0]] < sv[idx[2]]) { int x = idx[0]; idx[0] = idx[2]; idx[2] = x; }
        if (sv[idx[1]] < sv[idx[2]]) { int x = idx[1]; idx[1] = idx[2]; idx[2] = x; }
        double U[3][3], Vs[3][3];
        for (int j = 0; j < 3; ++j) {
            const int jj = idx[j];
            const double inv = 1.0 / fmax(sv[jj], 1e-300);
            for (int i = 0; i < 3; ++i) {
                U[i][j] = A[i][jj] * inv;
                Vs[i][j] = V[i][jj];
            }
        }
        double R[3][3];
        for (int i = 0; i < 3; ++i)
            for (int j = 0; j < 3; ++j)
                R[i][j] = Vs[i][0] * U[j][0] + Vs[i][1] * U[j][1] + Vs[i][2] * U[j][2];
        const double det = R[0][0] * (R[1][1] * R[2][2] - R[1][2] * R[2][1])
                         - R[0][1] * (R[1][0] * R[2][2] - R[1][2] * R[2][0])
                         + R[0][2] * (R[1][0] * R[2][1] - R[1][1] * R[2][0]);
        if (det < 0.0) {
            for (int i = 0; i < 3; ++i) Vs[i][2] = -Vs[i][2];
            for (int i = 0; i < 3; ++i)
                for (int j = 0; j < 3; ++j)
                    R[i][j] = Vs[i][0] * U[j][0] + Vs[i][1] * U[j][1] + Vs[i][2] * U[j][2];
        }
        double tr[3];
        for (int i = 0; i < 3; ++i)
            tr[i] = cb[i] - (R[i][0] * ca[0] + R[i][1] * ca[1] + R[i][2] * ca[2]);
        float* o = out + b * 12;
        for (int i = 0; i < 3; ++i) {
            o[i * 4 + 0] = (float)R[i][0];
            o[i * 4 + 1] = (float)R[i][1];
            o[i * 4 + 2] = (float)R[i][2];
            o[i * 4 + 3] = (float)tr[i];
        }
    }
}

// ---------------------------------------------------------------------------
extern "C" void kernel_launch(void* const* d_in, const int* in_sizes, int n_in,
                              void* d_out, int out_size, void* d_ws, size_t ws_size,
                              hipStream_t stream) {
    const float* f1 = (const float*)d_in[0];
    const float* f2 = (const float*)d_in[1];
    const float* p1 = (const float*)d_in[2];
    const float* p2 = (const float*)d_in[3];
    float* out = (float*)d_out;

    const size_t AL = 256;
    const size_t szK   = (size_t)NN * MM * 2;
    const size_t szF1  = (size_t)NN * CC * 2;
    const size_t szF2  = (size_t)MM * CC * 2;
    const size_t szB   = (size_t)MM * 4;
    const size_t szKTa = (size_t)MM * 4;
    const size_t szBp4 = (size_t)MM * 16;
    const size_t szWc4 = (size_t)NN * 16;
    const size_t per_batch = szK + szF1 + szF2 + szB + szKTa + szBp4 + szWc4 + 8 * AL;

    int NS = (int)(ws_size / per_batch);
    if (NS > NB) NS = NB;
    if (NS < 1) NS = 1;

    char* base = (char*)d_ws;
    size_t off = 0;
    auto carve = [&](size_t bytes) -> char* {
        char* p = base + off;
        off += (bytes + AL - 1) & ~(AL - 1);
        return p;
    };
    u16*   Ks   = (u16*)  carve((size_t)NS * szK);
    u16*   f1s  = (u16*)  carve((size_t)NS * szF1);
    u16*   f2s  = (u16*)  carve((size_t)NS * szF2);
    float* bvec = (float*)carve((size_t)NS * szB);
    float* KTa  = (float*)carve((size_t)NS * szKTa);
    float* bp4  = (float*)carve((size_t)NS * szBp4);
    float* wc4  = (float*)carve((size_t)NS * szWc4);

    for (int b0 = 0; b0 < NB; b0 += NS) {
        const int cnt = (NB - b0 < NS) ? (NB - b0) : NS;

        norm_kernel<<<cnt * NN / 4, 256, 0, stream>>>(f1 + (size_t)b0 * NN * CC, f1s);
        norm_kernel<<<cnt * MM / 4, 256, 0, stream>>>(f2 + (size_t)b0 * MM * CC, f2s);
        zero_kernel<<<cnt * MM / 256, 256, 0, stream>>>(KTa);
        gemm_exp_kernel<<<dim3(MM / 128, NN / 128, cnt), 256, 0, stream>>>(f1s, f2s, Ks, KTa);
        bfin_kernel<<<cnt * MM / 256, 256, 0, stream>>>(KTa, bvec);

        for (int it = 0; it < 9; ++it) {
            fused_kernel<<<cnt * 128, 256, 0, stream>>>(Ks, bvec, KTa);
            bfin_kernel<<<cnt * MM / 256, 256, 0, stream>>>(KTa, bvec);
        }

        bp4_kernel<<<cnt * MM / 256, 256, 0, stream>>>(bvec, p2 + (size_t)b0 * MM * 3, bp4);
        final_kernel<<<cnt * 64, 256, 0, stream>>>(Ks, bp4, wc4);
        kabsch_kernel<<<cnt, 256, 0, stream>>>(wc4, p1 + (size_t)b0 * NN * 3, out + (size_t)b0 * 12);
    }

    (void)in_sizes; (void)n_in; (void)out_size;
}